// Round 5
// baseline (280.962 us; speedup 1.0000x reference)
//
#include <hip/hip_runtime.h>
#include <hip/hip_bf16.h>
#include <cstdint>

// Problem constants
#define SDIM 160
#define HDIM 768
#define HALF 384
#define ODIM 260
#define OPAD 272           // 17 * 16
#define CHUNK_BYTES 34816  // 8 kgroups * 272 rows * 16B
#define WS_BF16 577536     // u16 elements before flags
#define WS_NEED (2*WS_BF16 + 16)

typedef __attribute__((ext_vector_type(8))) short short8;
typedef __attribute__((ext_vector_type(4))) float floatx4;

static __device__ __forceinline__ float bf2f(unsigned short u) {
    union { unsigned int i; float f; } v; v.i = ((unsigned int)u) << 16; return v.f;
}
static __device__ __forceinline__ unsigned short f2bf(float x) {
    __hip_bfloat16 h = __float2bfloat16(x);
    return *reinterpret_cast<unsigned short*>(&h);
}
static __device__ __forceinline__ float q(float x) { return bf2f(f2bf(x)); }

// ---------------------------------------------------------------------------
// Kernel 1: RoPE(y fp32) -> yb bf16; W2 fp32 -> W2b bf16 [kg 96][row 272][8];
// zero the fallback flags.
// ---------------------------------------------------------------------------
__global__ __launch_bounds__(256) void prep_kernel(
    const float* __restrict__ y, const float* __restrict__ W2,
    unsigned short* __restrict__ yb, unsigned short* __restrict__ W2b,
    int* __restrict__ flags) {
    int bid = blockIdx.x;
    int t = threadIdx.x;
    if (bid == 0 && t == 0) { flags[0] = 0; flags[1] = 0; }
    if (bid < SDIM) {
        int s = bid;
        for (int p = t; p < HALF; p += 256) {
            float invf = __expf(-(2.0f * (float)p / (float)HDIM) * 9.210340371976184f);
            float th = (float)s * invf;
            float c = cosf(th), sn = sinf(th);
            float y0 = y[s * HDIM + 2 * p], y1 = y[s * HDIM + 2 * p + 1];
            yb[s * HDIM + 2 * p]     = f2bf(y0 * c - y1 * sn);
            yb[s * HDIM + 2 * p + 1] = f2bf(y1 * c + y0 * sn);
        }
    } else {
        int idx = (bid - SDIM) * 256 + t;       // [0, 96*272*8)
        int kg = idx / (OPAD * 8);
        int rem = idx - kg * (OPAD * 8);
        int row = rem >> 3, e = rem & 7;
        W2b[idx] = (row < ODIM) ? f2bf(W2[row * HDIM + kg * 8 + e])
                                : (unsigned short)0;
    }
}

// ---------------------------------------------------------------------------
// Kernel 2 (MFMA path): L[s][o] = yrot[s]·W1[o,0:768];
// R[s][o] = yrot[s]·W1[o,768:]+b1[o]. C/D: row=q*4+r, col=lane&15.
// ---------------------------------------------------------------------------
__global__ __launch_bounds__(256) void lr_kernel(
    const unsigned short* __restrict__ yb, const float* __restrict__ W1,
    const float* __restrict__ b1,
    unsigned short* __restrict__ Lb, unsigned short* __restrict__ Rb) {
    int w = threadIdx.x >> 6;
    int l = threadIdx.x & 63;
    int l16 = l & 15, qd = l >> 4;
    int wg = blockIdx.x * 4 + w;     // [0,960)
    int mo = wg % 96;                // o2-tile
    int st = wg / 96;                // s-tile

    int o2in = mo * 16 + l16;
    int wrow = o2in & 767;
    int wcol0 = (o2in >= 768) ? 768 : 0;
    const float* wp = W1 + wrow * 1536 + wcol0;
    int s_in = st * 16 + l16;

    floatx4 acc = {0.0f, 0.0f, 0.0f, 0.0f};
    #pragma unroll
    for (int kk = 0; kk < 24; ++kk) {
        int k = kk * 32 + qd * 8;
        float4 wa = *reinterpret_cast<const float4*>(wp + k);
        float4 wb = *reinterpret_cast<const float4*>(wp + k + 4);
        short8 a;
        a[0] = f2bf(wa.x); a[1] = f2bf(wa.y); a[2] = f2bf(wa.z); a[3] = f2bf(wa.w);
        a[4] = f2bf(wb.x); a[5] = f2bf(wb.y); a[6] = f2bf(wb.z); a[7] = f2bf(wb.w);
        union { uint4 u; short8 s; } bu;
        bu.u = *reinterpret_cast<const uint4*>(yb + s_in * HDIM + k);
        acc = __builtin_amdgcn_mfma_f32_16x16x32_bf16(a, bu.s, acc, 0, 0, 0);
    }

    int s_out = st * 16 + l16;
    int o2b = mo * 16 + qd * 4;
    unsigned short out4[4];
    if (o2b < 768) {
        #pragma unroll
        for (int r = 0; r < 4; ++r) out4[r] = f2bf(acc[r]);
        *reinterpret_cast<uint2*>(Lb + s_out * HDIM + o2b) =
            *reinterpret_cast<uint2*>(out4);
    } else {
        int ob = o2b - 768;
        #pragma unroll
        for (int r = 0; r < 4; ++r) out4[r] = f2bf(acc[r] + b1[ob + r]);
        *reinterpret_cast<uint2*>(Rb + s_out * HDIM + ob) =
            *reinterpret_cast<uint2*>(out4);
    }
}

// ---------------------------------------------------------------------------
// Kernel 3: verify L/R at 128 sample points vs serial dots; set flags[0].
// ---------------------------------------------------------------------------
__global__ __launch_bounds__(256) void verify_lr_kernel(
    const unsigned short* __restrict__ yb, const float* __restrict__ W1,
    const float* __restrict__ b1,
    const unsigned short* __restrict__ Lb, const unsigned short* __restrict__ Rb,
    int* __restrict__ flags) {
    int t = threadIdx.x;
    if (t >= 128) return;
    int bad = 0;
    if (t < 64) {
        int s = (t * 37 + 11) % SDIM;
        int o = (t * 113 + 29) % HDIM;
        float a0 = 0.0f;
        for (int k = 0; k < HDIM; ++k)
            a0 += q(W1[o * 1536 + k]) * bf2f(yb[s * HDIM + k]);
        if (fabsf(bf2f(Lb[s * HDIM + o]) - q(a0)) > 0.05f) bad = 1;
    } else {
        int tt = t - 64;
        int s = (tt * 53 + 7) % SDIM;
        int o = (tt * 97 + 13) % HDIM;
        float a0 = 0.0f;
        for (int k = 0; k < HDIM; ++k)
            a0 += q(W1[o * 1536 + 768 + k]) * bf2f(yb[s * HDIM + k]);
        a0 += b1[o];
        if (fabsf(bf2f(Rb[s * HDIM + o]) - q(a0)) > 0.05f) bad = 1;
    }
    if (bad) atomicOr(&flags[0], 1);
}

// ---------------------------------------------------------------------------
// Kernel 4: pure-VALU fallback — recompute ALL of L/R if flags[0] set.
// ---------------------------------------------------------------------------
__global__ __launch_bounds__(256) void lr_fallback_kernel(
    const unsigned short* __restrict__ yb, const float* __restrict__ W1,
    const float* __restrict__ b1,
    unsigned short* __restrict__ Lb, unsigned short* __restrict__ Rb,
    const int* __restrict__ flags) {
    if (flags[0] == 0) return;
    int idx = blockIdx.x * 256 + threadIdx.x;   // [0, 160*1536)
    int s = idx / 1536;
    int o2 = idx - s * 1536;
    const unsigned short* yrow = yb + s * HDIM;
    if (o2 < 768) {
        const float* wp = W1 + o2 * 1536;
        float a0 = 0.0f;
        for (int k = 0; k < HDIM; ++k) a0 += q(wp[k]) * bf2f(yrow[k]);
        Lb[s * HDIM + o2] = f2bf(a0);
    } else {
        int ob = o2 - 768;
        const float* wp = W1 + ob * 1536 + 768;
        float a0 = 0.0f;
        for (int k = 0; k < HDIM; ++k) a0 += q(wp[k]) * bf2f(yrow[k]);
        Rb[s * HDIM + ob] = f2bf(a0 + b1[ob]);
    }
}

// ---------------------------------------------------------------------------
// Kernel 5 (MFMA path): out[rel,i,j,tag] = sigmoid(W2·relu(l_i+r_j)+b2).
// ---------------------------------------------------------------------------
__global__ __launch_bounds__(128, 2) void main_kernel(
    const unsigned short* __restrict__ Lb, const unsigned short* __restrict__ Rb,
    const unsigned short* __restrict__ W2b,
    const float* __restrict__ b2, float* __restrict__ out) {
    __shared__ __align__(16) unsigned char lds[CHUNK_BYTES];

    int w = threadIdx.x >> 6;
    int l = threadIdx.x & 63;
    int l16 = l & 15, qd = l >> 4;
    int i0 = blockIdx.x * 4;
    int j0 = blockIdx.y * 16;
    int j = j0 + l16;

    floatx4 acc[2][17];
    #pragma unroll
    for (int c = 0; c < 2; ++c)
        #pragma unroll
        for (int mt = 0; mt < 17; ++mt)
            acc[c][mt] = (floatx4){0.0f, 0.0f, 0.0f, 0.0f};

    const unsigned short* Lrow0 = Lb + (i0 + 2 * w) * HDIM;
    const unsigned short* Lrow1 = Lb + (i0 + 2 * w + 1) * HDIM;
    const unsigned short* Rrow  = Rb + j * HDIM;

    for (int kc = 0; kc < 12; ++kc) {
        __syncthreads();
        const uint4* gsrc = reinterpret_cast<const uint4*>(
            reinterpret_cast<const unsigned char*>(W2b) + kc * CHUNK_BYTES);
        uint4* ldsv = reinterpret_cast<uint4*>(lds);
        #pragma unroll
        for (int it = 0; it < 17; ++it) {
            int idx = it * 128 + threadIdx.x;   // 2176 uint4 per chunk
            ldsv[idx] = gsrc[idx];
        }
        __syncthreads();
        #pragma unroll
        for (int ks = 0; ks < 2; ++ks) {
            int k = kc * 64 + ks * 32 + qd * 8;
            short8 bfrag[2];
            #pragma unroll
            for (int c = 0; c < 2; ++c) {
                const unsigned short* Lr = c ? Lrow1 : Lrow0;
                union { uint4 u; unsigned short us[8]; } lu, ru;
                lu.u = *reinterpret_cast<const uint4*>(Lr + k);
                ru.u = *reinterpret_cast<const uint4*>(Rrow + k);
                short8 hb;
                #pragma unroll
                for (int e = 0; e < 8; ++e) {
                    float hv = bf2f(lu.us[e]) + bf2f(ru.us[e]);
                    hb[e] = (short)f2bf(fmaxf(hv, 0.0f));
                }
                bfrag[c] = hb;
            }
            int ldsbase = ((ks * 4 + qd) * OPAD + l16) * 16;
            #pragma unroll
            for (int mt = 0; mt < 17; ++mt) {
                union { uint4 u; short8 s; } au;
                au.u = *reinterpret_cast<const uint4*>(lds + ldsbase + mt * 256);
                acc[0][mt] = __builtin_amdgcn_mfma_f32_16x16x32_bf16(
                    au.s, bfrag[0], acc[0][mt], 0, 0, 0);
                acc[1][mt] = __builtin_amdgcn_mfma_f32_16x16x32_bf16(
                    au.s, bfrag[1], acc[1][mt], 0, 0, 0);
            }
        }
    }

    #pragma unroll
    for (int c = 0; c < 2; ++c) {
        int i = i0 + 2 * w + c;
        #pragma unroll
        for (int mt = 0; mt < 17; ++mt) {
            int ob = mt * 16 + qd * 4;
            if (ob < ODIM) {
                float4 bv = *reinterpret_cast<const float4*>(b2 + ob);
                int rel = ob >> 2;
                float4 v;
                v.x = 1.0f / (1.0f + __expf(-(acc[c][mt][0] + bv.x)));
                v.y = 1.0f / (1.0f + __expf(-(acc[c][mt][1] + bv.y)));
                v.z = 1.0f / (1.0f + __expf(-(acc[c][mt][2] + bv.z)));
                v.w = 1.0f / (1.0f + __expf(-(acc[c][mt][3] + bv.w)));
                *reinterpret_cast<float4*>(out + (((rel * SDIM) + i) * SDIM + j) * 4) = v;
            }
        }
    }
}

// ---------------------------------------------------------------------------
// Kernel 6: verify 16 output samples vs serial recompute from Lb/Rb/W2.
// ---------------------------------------------------------------------------
__global__ __launch_bounds__(256) void verify_main_kernel(
    const unsigned short* __restrict__ Lb, const unsigned short* __restrict__ Rb,
    const float* __restrict__ W2, const float* __restrict__ b2,
    const float* __restrict__ out, int* __restrict__ flags) {
    __shared__ float red[256];
    int b = blockIdx.x, t = threadIdx.x;
    int i = (b * 37 + 3) % SDIM;
    int j = (b * 59 + 8) % SDIM;
    int o = (b * 31 + 2) % ODIM;
    float partial = 0.0f;
    for (int hp = t; hp < HDIM; hp += 256) {
        float h = fmaxf(bf2f(Lb[i * HDIM + hp]) + bf2f(Rb[j * HDIM + hp]), 0.0f);
        partial += q(h) * q(W2[o * HDIM + hp]);
    }
    red[t] = partial;
    __syncthreads();
    for (int stp = 128; stp > 0; stp >>= 1) {
        if (t < stp) red[t] += red[t + stp];
        __syncthreads();
    }
    if (t == 0) {
        float v = 1.0f / (1.0f + __expf(-(red[0] + b2[o])));
        float got = out[(((o >> 2) * SDIM + i) * SDIM + j) * 4 + (o & 3)];
        if (fabsf(v - got) > 0.008f) atomicOr(&flags[1], 1);
    }
}

// ---------------------------------------------------------------------------
// Kernel 7: pure-VALU fallback — recompute ALL outputs if flags[1] set.
// One block per (i,j); h staged in LDS; each thread covers o = t, t+256.
// ---------------------------------------------------------------------------
__global__ __launch_bounds__(256) void main_fallback_kernel(
    const unsigned short* __restrict__ Lb, const unsigned short* __restrict__ Rb,
    const float* __restrict__ W2, const float* __restrict__ b2,
    float* __restrict__ out, const int* __restrict__ flags) {
    if (flags[1] == 0) return;
    __shared__ float h[HDIM];
    int bid = blockIdx.x;               // [0, 25600)
    int i = bid / SDIM, j = bid % SDIM;
    int t = threadIdx.x;
    for (int hp = t; hp < HDIM; hp += 256)
        h[hp] = fmaxf(bf2f(Lb[i * HDIM + hp]) + bf2f(Rb[j * HDIM + hp]), 0.0f);
    __syncthreads();
    for (int o = t; o < ODIM; o += 256) {
        const float* wp = W2 + o * HDIM;
        float a0 = 0.0f;
        for (int hp = 0; hp < HDIM; ++hp) a0 += h[hp] * wp[hp];
        float v = 1.0f / (1.0f + __expf(-(a0 + b2[o])));
        out[(((o >> 2) * SDIM + i) * SDIM + j) * 4 + (o & 3)] = v;
    }
}

__global__ void ws_too_small_kernel(float* out) { out[0] = 999.0f; }

extern "C" void kernel_launch(void* const* d_in, const int* in_sizes, int n_in,
                              void* d_out, int out_size, void* d_ws, size_t ws_size,
                              hipStream_t stream) {
    const float* y  = (const float*)d_in[0];
    // d_in[1] = event_idx : unused by the reference
    const float* W1 = (const float*)d_in[2];
    const float* b1 = (const float*)d_in[3];
    const float* W2 = (const float*)d_in[4];
    const float* b2 = (const float*)d_in[5];
    float* out = (float*)d_out;

    if (ws_size < (size_t)WS_NEED) {
        ws_too_small_kernel<<<dim3(1), dim3(1), 0, stream>>>(out);
        return;
    }

    unsigned short* yb  = (unsigned short*)d_ws;       // 160*768
    unsigned short* Lb  = yb + SDIM * HDIM;            // 160*768
    unsigned short* Rb  = Lb + SDIM * HDIM;            // 160*768
    unsigned short* W2b = Rb + SDIM * HDIM;            // 96*272*8
    int* flags = (int*)((char*)d_ws + 2 * WS_BF16);    // 2 ints

    prep_kernel<<<dim3(SDIM + 816), dim3(256), 0, stream>>>(y, W2, yb, W2b, flags);
    lr_kernel<<<dim3(240), dim3(256), 0, stream>>>(yb, W1, b1, Lb, Rb);
    verify_lr_kernel<<<dim3(1), dim3(256), 0, stream>>>(yb, W1, b1, Lb, Rb, flags);
    lr_fallback_kernel<<<dim3(960), dim3(256), 0, stream>>>(yb, W1, b1, Lb, Rb, flags);
    main_kernel<<<dim3(40, 10), dim3(128), 0, stream>>>(Lb, Rb, W2b, b2, out);
    verify_main_kernel<<<dim3(16), dim3(256), 0, stream>>>(Lb, Rb, W2, b2, out, flags);
    main_fallback_kernel<<<dim3(25600), dim3(256), 0, stream>>>(Lb, Rb, W2, b2, out, flags);
}

// Round 6
// 144.378 us; speedup vs baseline: 1.9460x; 1.9460x over previous
//
#include <hip/hip_runtime.h>
#include <hip/hip_bf16.h>
#include <cstdint>

// Problem constants
#define SDIM 160
#define HDIM 768
#define HALF 384
#define ODIM 260
#define OPAD 272           // 17 * 16
#define CHUNK_BYTES 34816  // 8 kgroups * 272 rows * 16B (W2b chunk)
// Workspace layout (bytes): flags@0(16) yb@16 Lb@245776 Rb@491536 W2b@737296
//                           W1b@1155088 end@3514384
#define WS_SMALL 1155088
#define WS_BIG   3514384

typedef __attribute__((ext_vector_type(8))) short short8;
typedef __attribute__((ext_vector_type(4))) float floatx4;

static __device__ __forceinline__ float bf2f(unsigned short u) {
    union { unsigned int i; float f; } v; v.i = ((unsigned int)u) << 16; return v.f;
}
static __device__ __forceinline__ unsigned short f2bf(float x) {
    __hip_bfloat16 h = __float2bfloat16(x);
    return *reinterpret_cast<unsigned short*>(&h);
}
static __device__ __forceinline__ float q(float x) { return bf2f(f2bf(x)); }

// ---------------------------------------------------------------------------
// Kernel 1: RoPE(y) -> yb bf16; W2 -> W2b bf16 [kg96][row272][8] (pad rows 0);
// (big path) W1 -> W1b bf16 [kg96][row1536][8] where row<768 = L-half,
// row>=768 = R-half of W1. Zeroes flags.
// ---------------------------------------------------------------------------
__global__ __launch_bounds__(256) void prep_kernel(
    const float* __restrict__ y, const float* __restrict__ W1,
    const float* __restrict__ W2,
    unsigned short* __restrict__ yb, unsigned short* __restrict__ W2b,
    unsigned short* __restrict__ W1b, int* __restrict__ flags) {
    int bid = blockIdx.x;
    int t = threadIdx.x;
    if (bid == 0 && t == 0) { flags[0] = 0; flags[1] = 0; }
    if (bid < SDIM) {
        int s = bid;
        for (int p = t; p < HALF; p += 256) {
            float invf = __expf(-(2.0f * (float)p / (float)HDIM) * 9.210340371976184f);
            float th = (float)s * invf;
            float c = cosf(th), sn = sinf(th);
            float y0 = y[s * HDIM + 2 * p], y1 = y[s * HDIM + 2 * p + 1];
            yb[s * HDIM + 2 * p]     = f2bf(y0 * c - y1 * sn);
            yb[s * HDIM + 2 * p + 1] = f2bf(y1 * c + y0 * sn);
        }
    } else if (bid < SDIM + 816) {
        int idx = (bid - SDIM) * 256 + t;       // [0, 96*272*8)
        int kg = idx / (OPAD * 8);
        int rem = idx - kg * (OPAD * 8);
        int row = rem >> 3, e = rem & 7;
        W2b[idx] = (row < ODIM) ? f2bf(W2[row * HDIM + kg * 8 + e])
                                : (unsigned short)0;
    } else {
        int idx = (bid - SDIM - 816) * 256 + t; // [0, 96*1536*8)
        int kg = idx / 12288;
        int rem = idx - kg * 12288;
        int row = rem >> 3, e = rem & 7;
        float v = (row < 768) ? W1[row * 1536 + kg * 8 + e]
                              : W1[(row - 768) * 1536 + 768 + kg * 8 + e];
        W1b[idx] = f2bf(v);
    }
}

// ---------------------------------------------------------------------------
// Kernel 2 (clone of proven main pattern): L[s][o]=yrot[s]·W1[o,:768];
// R[s][o]=yrot[s]·W1[o,768:]+b1[o]. A = W1b chunk from LDS, B = yb registers.
// Block = 2 waves; wave covers 1 s-tile x 16 m-tiles. Grid (6 mb, 5 nb).
// ---------------------------------------------------------------------------
__global__ __launch_bounds__(128, 2) void lr2_kernel(
    const unsigned short* __restrict__ yb, const unsigned short* __restrict__ W1b,
    const float* __restrict__ b1,
    unsigned short* __restrict__ Lb, unsigned short* __restrict__ Rb) {
    __shared__ __align__(16) unsigned char lds[32768];  // 8 kg x 256 rows x 16B

    int w = threadIdx.x >> 6;
    int l = threadIdx.x & 63;
    int l16 = l & 15, qd = l >> 4;
    int mb = blockIdx.x;                 // [0,6) -> o2 base mb*256
    int nb = blockIdx.y;                 // [0,5)
    int s_in = (nb * 2 + w) * 16 + l16;  // [0,160)

    floatx4 acc[16];
    #pragma unroll
    for (int mt = 0; mt < 16; ++mt) acc[mt] = (floatx4){0.0f, 0.0f, 0.0f, 0.0f};

    const unsigned short* yrow = yb + s_in * HDIM;
    const uint4* w1v = reinterpret_cast<const uint4*>(W1b);
    uint4* ldsv = reinterpret_cast<uint4*>(lds);

    for (int kc = 0; kc < 12; ++kc) {
        __syncthreads();
        #pragma unroll
        for (int it = 0; it < 16; ++it) {
            int idx = it * 128 + threadIdx.x;    // [0,2048)
            int kgl = idx >> 8, u = idx & 255;
            ldsv[idx] = w1v[(kc * 8 + kgl) * 1536 + mb * 256 + u];
        }
        __syncthreads();
        #pragma unroll
        for (int ks = 0; ks < 2; ++ks) {
            int k = kc * 64 + ks * 32 + qd * 8;
            union { uint4 u; short8 s; } bu;
            bu.u = *reinterpret_cast<const uint4*>(yrow + k);
            int ldsbase = ((ks * 4 + qd) * 256 + l16) * 16;
            #pragma unroll
            for (int mt = 0; mt < 16; ++mt) {
                union { uint4 u; short8 s; } au;
                au.u = *reinterpret_cast<const uint4*>(lds + ldsbase + mt * 256);
                acc[mt] = __builtin_amdgcn_mfma_f32_16x16x32_bf16(
                    au.s, bu.s, acc[mt], 0, 0, 0);
            }
        }
    }

    #pragma unroll
    for (int mt = 0; mt < 16; ++mt) {
        int o2 = mb * 256 + mt * 16 + qd * 4;
        unsigned short out4[4];
        if (o2 < 768) {
            #pragma unroll
            for (int r = 0; r < 4; ++r) out4[r] = f2bf(acc[mt][r]);
            *reinterpret_cast<uint2*>(Lb + s_in * HDIM + o2) =
                *reinterpret_cast<uint2*>(out4);
        } else {
            int ob = o2 - 768;
            #pragma unroll
            for (int r = 0; r < 4; ++r) out4[r] = f2bf(acc[mt][r] + b1[ob + r]);
            *reinterpret_cast<uint2*>(Rb + s_in * HDIM + ob) =
                *reinterpret_cast<uint2*>(out4);
        }
    }
}

// ---------------------------------------------------------------------------
// Kernel 3: verify L/R at 128 samples (parallel: 1 sample per block).
// ---------------------------------------------------------------------------
__global__ __launch_bounds__(256) void verify_lr_kernel(
    const unsigned short* __restrict__ yb, const float* __restrict__ W1,
    const float* __restrict__ b1,
    const unsigned short* __restrict__ Lb, const unsigned short* __restrict__ Rb,
    int* __restrict__ flags) {
    __shared__ float red[256];
    int b = blockIdx.x, t = threadIdx.x;
    int s, o; const float* wbase; float bias; const unsigned short* dst;
    if (b < 64) {
        s = (b * 37 + 11) % SDIM; o = (b * 113 + 29) % HDIM;
        wbase = W1 + o * 1536; bias = 0.0f; dst = Lb + s * HDIM + o;
    } else {
        int bb = b - 64;
        s = (bb * 53 + 7) % SDIM; o = (bb * 97 + 13) % HDIM;
        wbase = W1 + o * 1536 + 768; bias = b1[o]; dst = Rb + s * HDIM + o;
    }
    float a0 = 0.0f;
    for (int k = t; k < HDIM; k += 256) a0 += q(wbase[k]) * bf2f(yb[s * HDIM + k]);
    red[t] = a0;
    __syncthreads();
    for (int stp = 128; stp > 0; stp >>= 1) {
        if (t < stp) red[t] += red[t + stp];
        __syncthreads();
    }
    if (t == 0) {
        if (fabsf(bf2f(*dst) - q(red[0] + bias)) > 0.05f) atomicOr(&flags[0], 1);
    }
}

// ---------------------------------------------------------------------------
// Kernel 4: pure-VALU fallback — recompute ALL of L/R if flagged (or forced).
// ---------------------------------------------------------------------------
__global__ __launch_bounds__(256) void lr_fallback_kernel(
    const unsigned short* __restrict__ yb, const float* __restrict__ W1,
    const float* __restrict__ b1,
    unsigned short* __restrict__ Lb, unsigned short* __restrict__ Rb,
    const int* __restrict__ flags, int force) {
    if (!force && flags[0] == 0) return;
    int idx = blockIdx.x * 256 + threadIdx.x;   // [0, 160*1536)
    int s = idx / 1536;
    int o2 = idx - s * 1536;
    const unsigned short* yrow = yb + s * HDIM;
    if (o2 < 768) {
        const float* wp = W1 + o2 * 1536;
        float a0 = 0.0f;
        for (int k = 0; k < HDIM; ++k) a0 += q(wp[k]) * bf2f(yrow[k]);
        Lb[s * HDIM + o2] = f2bf(a0);
    } else {
        int ob = o2 - 768;
        const float* wp = W1 + ob * 1536 + 768;
        float a0 = 0.0f;
        for (int k = 0; k < HDIM; ++k) a0 += q(wp[k]) * bf2f(yrow[k]);
        Rb[s * HDIM + ob] = f2bf(a0 + b1[ob]);
    }
}

// ---------------------------------------------------------------------------
// Kernel 5 (PROVEN, untouched): out[rel,i,j,tag]=sigmoid(W2·relu(l_i+r_j)+b2).
// ---------------------------------------------------------------------------
__global__ __launch_bounds__(128, 2) void main_kernel(
    const unsigned short* __restrict__ Lb, const unsigned short* __restrict__ Rb,
    const unsigned short* __restrict__ W2b,
    const float* __restrict__ b2, float* __restrict__ out) {
    __shared__ __align__(16) unsigned char lds[CHUNK_BYTES];

    int w = threadIdx.x >> 6;
    int l = threadIdx.x & 63;
    int l16 = l & 15, qd = l >> 4;
    int i0 = blockIdx.x * 4;
    int j0 = blockIdx.y * 16;
    int j = j0 + l16;

    floatx4 acc[2][17];
    #pragma unroll
    for (int c = 0; c < 2; ++c)
        #pragma unroll
        for (int mt = 0; mt < 17; ++mt)
            acc[c][mt] = (floatx4){0.0f, 0.0f, 0.0f, 0.0f};

    const unsigned short* Lrow0 = Lb + (i0 + 2 * w) * HDIM;
    const unsigned short* Lrow1 = Lb + (i0 + 2 * w + 1) * HDIM;
    const unsigned short* Rrow  = Rb + j * HDIM;

    for (int kc = 0; kc < 12; ++kc) {
        __syncthreads();
        const uint4* gsrc = reinterpret_cast<const uint4*>(
            reinterpret_cast<const unsigned char*>(W2b) + kc * CHUNK_BYTES);
        uint4* ldsv = reinterpret_cast<uint4*>(lds);
        #pragma unroll
        for (int it = 0; it < 17; ++it) {
            int idx = it * 128 + threadIdx.x;   // 2176 uint4 per chunk
            ldsv[idx] = gsrc[idx];
        }
        __syncthreads();
        #pragma unroll
        for (int ks = 0; ks < 2; ++ks) {
            int k = kc * 64 + ks * 32 + qd * 8;
            short8 bfrag[2];
            #pragma unroll
            for (int c = 0; c < 2; ++c) {
                const unsigned short* Lr = c ? Lrow1 : Lrow0;
                union { uint4 u; unsigned short us[8]; } lu, ru;
                lu.u = *reinterpret_cast<const uint4*>(Lr + k);
                ru.u = *reinterpret_cast<const uint4*>(Rrow + k);
                short8 hb;
                #pragma unroll
                for (int e = 0; e < 8; ++e) {
                    float hv = bf2f(lu.us[e]) + bf2f(ru.us[e]);
                    hb[e] = (short)f2bf(fmaxf(hv, 0.0f));
                }
                bfrag[c] = hb;
            }
            int ldsbase = ((ks * 4 + qd) * OPAD + l16) * 16;
            #pragma unroll
            for (int mt = 0; mt < 17; ++mt) {
                union { uint4 u; short8 s; } au;
                au.u = *reinterpret_cast<const uint4*>(lds + ldsbase + mt * 256);
                acc[0][mt] = __builtin_amdgcn_mfma_f32_16x16x32_bf16(
                    au.s, bfrag[0], acc[0][mt], 0, 0, 0);
                acc[1][mt] = __builtin_amdgcn_mfma_f32_16x16x32_bf16(
                    au.s, bfrag[1], acc[1][mt], 0, 0, 0);
            }
        }
    }

    #pragma unroll
    for (int c = 0; c < 2; ++c) {
        int i = i0 + 2 * w + c;
        #pragma unroll
        for (int mt = 0; mt < 17; ++mt) {
            int ob = mt * 16 + qd * 4;
            if (ob < ODIM) {
                float4 bv = *reinterpret_cast<const float4*>(b2 + ob);
                int rel = ob >> 2;
                float4 v;
                v.x = 1.0f / (1.0f + __expf(-(acc[c][mt][0] + bv.x)));
                v.y = 1.0f / (1.0f + __expf(-(acc[c][mt][1] + bv.y)));
                v.z = 1.0f / (1.0f + __expf(-(acc[c][mt][2] + bv.z)));
                v.w = 1.0f / (1.0f + __expf(-(acc[c][mt][3] + bv.w)));
                *reinterpret_cast<float4*>(out + (((rel * SDIM) + i) * SDIM + j) * 4) = v;
            }
        }
    }
}

// ---------------------------------------------------------------------------
// Kernel 6: verify 16 output samples vs serial recompute from Lb/Rb/W2.
// ---------------------------------------------------------------------------
__global__ __launch_bounds__(256) void verify_main_kernel(
    const unsigned short* __restrict__ Lb, const unsigned short* __restrict__ Rb,
    const float* __restrict__ W2, const float* __restrict__ b2,
    const float* __restrict__ out, int* __restrict__ flags) {
    __shared__ float red[256];
    int b = blockIdx.x, t = threadIdx.x;
    int i = (b * 37 + 3) % SDIM;
    int j = (b * 59 + 8) % SDIM;
    int o = (b * 31 + 2) % ODIM;
    float partial = 0.0f;
    for (int hp = t; hp < HDIM; hp += 256) {
        float h = fmaxf(bf2f(Lb[i * HDIM + hp]) + bf2f(Rb[j * HDIM + hp]), 0.0f);
        partial += q(h) * q(W2[o * HDIM + hp]);
    }
    red[t] = partial;
    __syncthreads();
    for (int stp = 128; stp > 0; stp >>= 1) {
        if (t < stp) red[t] += red[t + stp];
        __syncthreads();
    }
    if (t == 0) {
        float v = 1.0f / (1.0f + __expf(-(red[0] + b2[o])));
        float got = out[(((o >> 2) * SDIM + i) * SDIM + j) * 4 + (o & 3)];
        if (fabsf(v - got) > 0.008f) atomicOr(&flags[1], 1);
    }
}

// ---------------------------------------------------------------------------
// Kernel 7: pure-VALU fallback — recompute ALL outputs if flagged.
// ---------------------------------------------------------------------------
__global__ __launch_bounds__(256) void main_fallback_kernel(
    const unsigned short* __restrict__ Lb, const unsigned short* __restrict__ Rb,
    const float* __restrict__ W2, const float* __restrict__ b2,
    float* __restrict__ out, const int* __restrict__ flags) {
    if (flags[1] == 0) return;
    __shared__ float h[HDIM];
    int bid = blockIdx.x;               // [0, 25600)
    int i = bid / SDIM, j = bid % SDIM;
    int t = threadIdx.x;
    for (int hp = t; hp < HDIM; hp += 256)
        h[hp] = fmaxf(bf2f(Lb[i * HDIM + hp]) + bf2f(Rb[j * HDIM + hp]), 0.0f);
    __syncthreads();
    for (int o = t; o < ODIM; o += 256) {
        const float* wp = W2 + o * HDIM;
        float a0 = 0.0f;
        for (int hp = 0; hp < HDIM; ++hp) a0 += h[hp] * wp[hp];
        float v = 1.0f / (1.0f + __expf(-(a0 + b2[o])));
        out[(((o >> 2) * SDIM + i) * SDIM + j) * 4 + (o & 3)] = v;
    }
}

__global__ void ws_too_small_kernel(float* out) { out[0] = 999.0f; }

extern "C" void kernel_launch(void* const* d_in, const int* in_sizes, int n_in,
                              void* d_out, int out_size, void* d_ws, size_t ws_size,
                              hipStream_t stream) {
    const float* y  = (const float*)d_in[0];
    // d_in[1] = event_idx : unused by the reference
    const float* W1 = (const float*)d_in[2];
    const float* b1 = (const float*)d_in[3];
    const float* W2 = (const float*)d_in[4];
    const float* b2 = (const float*)d_in[5];
    float* out = (float*)d_out;

    if (ws_size < (size_t)WS_SMALL) {
        ws_too_small_kernel<<<dim3(1), dim3(1), 0, stream>>>(out);
        return;
    }

    int* flags = (int*)d_ws;                                      // @0
    unsigned short* yb  = (unsigned short*)((char*)d_ws + 16);    // 160*768
    unsigned short* Lb  = yb + SDIM * HDIM;
    unsigned short* Rb  = Lb + SDIM * HDIM;
    unsigned short* W2b = Rb + SDIM * HDIM;                       // 96*272*8
    unsigned short* W1b = W2b + 96 * OPAD * 8;                    // 96*1536*8

    if (ws_size >= (size_t)WS_BIG) {
        prep_kernel<<<dim3(SDIM + 816 + 4608), dim3(256), 0, stream>>>(
            y, W1, W2, yb, W2b, W1b, flags);
        lr2_kernel<<<dim3(6, 5), dim3(128), 0, stream>>>(yb, W1b, b1, Lb, Rb);
        verify_lr_kernel<<<dim3(128), dim3(256), 0, stream>>>(yb, W1, b1, Lb, Rb, flags);
        lr_fallback_kernel<<<dim3(960), dim3(256), 0, stream>>>(yb, W1, b1, Lb, Rb, flags, 0);
        main_kernel<<<dim3(40, 10), dim3(128), 0, stream>>>(Lb, Rb, W2b, b2, out);
        verify_main_kernel<<<dim3(16), dim3(256), 0, stream>>>(Lb, Rb, W2, b2, out, flags);
        main_fallback_kernel<<<dim3(25600), dim3(256), 0, stream>>>(Lb, Rb, W2, b2, out, flags);
    } else {
        // Small-ws path: round-5-proven pipeline (VALU lr, verified main).
        prep_kernel<<<dim3(SDIM + 816), dim3(256), 0, stream>>>(
            y, W1, W2, yb, W2b, W1b, flags);
        lr_fallback_kernel<<<dim3(960), dim3(256), 0, stream>>>(yb, W1, b1, Lb, Rb, flags, 1);
        main_kernel<<<dim3(40, 10), dim3(128), 0, stream>>>(Lb, Rb, W2b, b2, out);
    }
}